// Round 1
// 246.631 us; speedup vs baseline: 1.0378x; 1.0378x over previous
//
#include <hip/hip_runtime.h>
#include <cstddef>

#define E 512
#define H 8
#define D 64
#define BATCH 2
#define SEQ 4096

typedef __attribute__((ext_vector_type(8))) short bf16x8;   // MFMA A/B frag
typedef __attribute__((ext_vector_type(4))) float f32x4;    // 16x16 C/D frag
typedef __attribute__((ext_vector_type(16))) float f32x16;  // 32x32 C/D frag
typedef __attribute__((ext_vector_type(4))) unsigned uint4v;

__device__ __forceinline__ ushort f2bf(float f) {
  unsigned u = __builtin_bit_cast(unsigned, f);
  u += 0x7fff + ((u >> 16) & 1);  // RNE
  return (ushort)(u >> 16);
}
__device__ __forceinline__ float bf2f(ushort h) {
  return __builtin_bit_cast(float, (unsigned)h << 16);
}
__device__ __forceinline__ unsigned pk_bf16(float lo, float hi) {
#if __has_builtin(__builtin_amdgcn_cvt_pk_bf16_f32)
  typedef __attribute__((ext_vector_type(2))) __bf16 bfv2;
  bfv2 r = __builtin_amdgcn_cvt_pk_bf16_f32(lo, hi);
  return __builtin_bit_cast(unsigned, r);
#else
  return (unsigned)f2bf(lo) | ((unsigned)f2bf(hi) << 16);
#endif
}
__device__ __forceinline__ float fexp2(float x) {
#if __has_builtin(__builtin_amdgcn_exp2f)
  return __builtin_amdgcn_exp2f(x);
#else
  return exp2f(x);
#endif
}
// lanes[32:63] of a  <->  lanes[0:31] of b
__device__ __forceinline__ void permswap32(unsigned& a, unsigned& b) {
  asm volatile("v_permlane32_swap_b32 %0, %1" : "+v"(a), "+v"(b));
}

// ---------------------------------------------------------------------------
// Kernel 0: cast x -> bf16 hi/lo split (xh + xl ~= x to ~16 mantissa bits)
// ---------------------------------------------------------------------------
__global__ __launch_bounds__(256) void xcast(const float* __restrict__ x,
                                             ushort* __restrict__ xh,
                                             ushort* __restrict__ xl) {
  size_t i = ((size_t)blockIdx.x * 256 + threadIdx.x) * 4;
  float4 v = *(const float4*)&x[i];
  ushort4 h, l;
  h.x = f2bf(v.x); l.x = f2bf(v.x - bf2f(h.x));
  h.y = f2bf(v.y); l.y = f2bf(v.y - bf2f(h.y));
  h.z = f2bf(v.z); l.z = f2bf(v.z - bf2f(h.z));
  h.w = f2bf(v.w); l.w = f2bf(v.w - bf2f(h.w));
  *(ushort4*)&xh[i] = h;
  *(ushort4*)&xl[i] = l;
}

// ---------------------------------------------------------------------------
// Kernel 1a: fold weights. Block = 256 k-lanes x 8 n (8 fp32 accs).
// ---------------------------------------------------------------------------
__global__ __launch_bounds__(256) void fold_tiled(
    const float* __restrict__ wq, const float* __restrict__ wk,
    const float* __restrict__ rot, const float* __restrict__ ent,
    ushort* __restrict__ weffbT) {
  const int which = blockIdx.z;
  const float* w = which ? wk : wq;
  const float* r = which ? ent : rot;
  const int k = blockIdx.x * 256 + threadIdx.x;
  const int n0 = blockIdx.y * 8;
  float acc[8] = {};
  for (int j0 = 0; j0 < E; j0 += 16) {
    float wv_[16];
#pragma unroll
    for (int u = 0; u < 16; ++u) wv_[u] = w[(size_t)(j0 + u) * E + k];
#pragma unroll
    for (int u = 0; u < 16; ++u)
#pragma unroll
      for (int t = 0; t < 8; ++t)
        acc[t] += wv_[u] * r[(size_t)(j0 + u) * E + n0 + t];
  }
#pragma unroll
  for (int t = 0; t < 8; ++t)
    weffbT[(size_t)which * E * E + (size_t)(n0 + t) * E + k] = f2bf(acc[t]);
}

// Kernel 1b: weffT[2][n][k] = bf16(wv[n][k]) — identity layout, pure cast.
__global__ __launch_bounds__(256) void wv_cast(const float* __restrict__ wv,
                                               ushort* __restrict__ dst) {
  size_t i = ((size_t)blockIdx.x * 256 + threadIdx.x) * 4;
  float4 v = *(const float4*)&wv[i];
  ushort4 o;
  o.x = f2bf(v.x); o.y = f2bf(v.y); o.z = f2bf(v.z); o.w = f2bf(v.w);
  *(ushort4*)&dst[i] = o;
}

// ---------------------------------------------------------------------------
// Kernel 2: fused QKV GEMM (unchanged; software-pipelined staging).
// ---------------------------------------------------------------------------
#define LDA 40  // padded LDS stride (bf16): 80B

__global__ __launch_bounds__(256) void qkv_fused(
    const ushort* __restrict__ xhg, const ushort* __restrict__ xlg,
    const ushort* __restrict__ weffbT, ushort* __restrict__ qg,
    ushort* __restrict__ kg, ushort* __restrict__ vtg) {
  __shared__ ushort sm[5 * 64 * LDA];  // Ah | Al | B0 | B1 | B2
  ushort* Ah = sm;
  ushort* Al = sm + 64 * LDA;
  ushort* Bs = sm + 2 * 64 * LDA;
  ushort* vt_tile = Bs;  // epilogue reuse: 64*72 <= 3*64*40

  const int head = blockIdx.x;
  const int m0 = blockIdx.y * 64;
  const int tid = threadIdx.x;
  const int wave = tid >> 6, lane = tid & 63;
  const int l15 = lane & 15, quad = lane >> 4;
  const int ar = tid >> 2, ac8 = (tid & 3) * 8;  // 64x32 tile staging slot

  const ushort* arow = xhg + (size_t)(m0 + ar) * E + ac8;
  const ushort* lrow = xlg + (size_t)(m0 + ar) * E + ac8;
  const ushort* b0row = weffbT + (size_t)(head * 64 + ar) * E + ac8;

  f32x4 acc[3][4];
#pragma unroll
  for (int w = 0; w < 3; ++w)
#pragma unroll
    for (int nt = 0; nt < 4; ++nt) acc[w][nt] = (f32x4){0.f, 0.f, 0.f, 0.f};

  // preload tile k0=0
  uint4 pa_h = *(const uint4*)&arow[0];
  uint4 pa_l = *(const uint4*)&lrow[0];
  uint4 pb0 = *(const uint4*)&b0row[0];
  uint4 pb1 = *(const uint4*)&b0row[E * E];
  uint4 pb2 = *(const uint4*)&b0row[2 * E * E];

  for (int k0 = 0; k0 < E; k0 += 32) {
    __syncthreads();
    *(uint4*)&Ah[ar * LDA + ac8] = pa_h;
    *(uint4*)&Al[ar * LDA + ac8] = pa_l;
    *(uint4*)&Bs[0 * 64 * LDA + ar * LDA + ac8] = pb0;
    *(uint4*)&Bs[1 * 64 * LDA + ar * LDA + ac8] = pb1;
    *(uint4*)&Bs[2 * 64 * LDA + ar * LDA + ac8] = pb2;
    __syncthreads();

    const int kn = (k0 + 32 < E) ? k0 + 32 : 0;
    pa_h = *(const uint4*)&arow[kn];
    pa_l = *(const uint4*)&lrow[kn];
    pb0 = *(const uint4*)&b0row[kn];
    pb1 = *(const uint4*)&b0row[E * E + kn];
    pb2 = *(const uint4*)&b0row[2 * E * E + kn];

    bf16x8 ah = *(const bf16x8*)&Ah[(wave * 16 + l15) * LDA + quad * 8];
    bf16x8 al = *(const bf16x8*)&Al[(wave * 16 + l15) * LDA + quad * 8];
#pragma unroll
    for (int w = 0; w < 3; ++w)
#pragma unroll
      for (int nt = 0; nt < 4; ++nt) {
        bf16x8 bf = *(const bf16x8*)&Bs[w * 64 * LDA + (nt * 16 + l15) * LDA +
                                        quad * 8];
        acc[w][nt] =
            __builtin_amdgcn_mfma_f32_16x16x32_bf16(ah, bf, acc[w][nt], 0, 0, 0);
        acc[w][nt] =
            __builtin_amdgcn_mfma_f32_16x16x32_bf16(al, bf, acc[w][nt], 0, 0, 0);
      }
  }

  const int b = m0 >> 12;
  const int s_base = m0 & (SEQ - 1);
  const float QSCALE = 0.125f * 1.44269504f;  // fold 1/sqrt(D)*log2(e) into q

#pragma unroll
  for (int w = 0; w < 2; ++w) {
    ushort* dst = (w == 0) ? qg : kg;
    float sc = (w == 0) ? QSCALE : 1.0f;
#pragma unroll
    for (int nt = 0; nt < 4; ++nt)
#pragma unroll
      for (int r = 0; r < 4; ++r) {
        float v = acc[w][nt][r] * sc;
        float vo = __shfl_xor(v, 1);
        if (!(lane & 1)) {
          int s = s_base + wave * 16 + quad * 4 + r;
          size_t ix = ((size_t)(b * H + head) * SEQ + s) * D + nt * 16 + l15;
          *(unsigned*)&dst[ix] = pk_bf16(v, vo);
        }
      }
  }

  __syncthreads();  // Bs frag reads done in all waves before reuse
#pragma unroll
  for (int nt = 0; nt < 4; ++nt) {
    uint2 w2;
    w2.x = pk_bf16(acc[2][nt][0], acc[2][nt][1]);
    w2.y = pk_bf16(acc[2][nt][2], acc[2][nt][3]);
    *(uint2*)&vt_tile[(nt * 16 + l15) * 72 + wave * 16 + quad * 4] = w2;
  }
  __syncthreads();
  {
    int vr = tid >> 2, vs = (tid & 3) * 16;
    uint4 c0 = *(const uint4*)&vt_tile[vr * 72 + vs];
    uint4 c1 = *(const uint4*)&vt_tile[vr * 72 + vs + 8];
    size_t vo = ((size_t)(b * H + head) * D + vr) * SEQ + s_base + vs;
    *(uint4*)&vtg[vo] = c0;
    *(uint4*)&vtg[vo + 8] = c1;
  }
}

// ---------------------------------------------------------------------------
// Kernel 3: flash attention, 32x32x16 MFMA, swapped QK^T -> P fully in
// registers (cvt_pk + v_permlane32_swap builds PV A-frags; NO P LDS
// round-trip). Max-free softmax, in-block K-split (2 groups x 4 waves),
// software-pipelined K/V staging. LDS halves to 37 KB.
//
// Layouts (verified mappings, guide §3):
//   C 32x32: col = lane&31, row = (reg&3) + 8*(reg>>2) + 4*(lane>>5)
//   A 32x32x16: lane holds A[row=lane&31][c=(lane>>5)*8 + j], j=0..7
//   B 32x32x16: lane holds B[c=(lane>>5)*8 + j][col=lane&31]
// S^T = K·Q^T  => lane owns P[q=qrow0+l31][k per reg pattern]; A-frag for
// PV needs the other half's k-quads only across the lane/lane+32 split,
// which one v_permlane32_swap per packed-word pair provides.
// ---------------------------------------------------------------------------
#define LDK 72  // padded stride (bf16): 144B, 16B-aligned

__global__ __launch_bounds__(512, 3) void attn_mfma(
    const ushort* __restrict__ qg, const ushort* __restrict__ kg,
    const ushort* __restrict__ vtg, float* __restrict__ out) {
  __shared__ ushort sm[4 * 64 * LDK + 256];  // Ks[2] | Vs[2] | lex
  ushort* Ks0 = sm;
  ushort* Vs0 = sm + 2 * 64 * LDK;
  float* lex = (float*)(sm + 4 * 64 * LDK);  // 128 floats

  const int qt = blockIdx.x;  // 0..31 (128 q-rows each)
  const int bh = blockIdx.y;
  const int tid = threadIdx.x;
  const int wave = tid >> 6;  // 0..7
  const int grp = wave >> 2, wq = wave & 3;
  const int lane = tid & 63;
  const int l31 = lane & 31, hi = lane >> 5;
  const int gtid = tid & 255;  // tid within group

  const ushort* qp = qg + (size_t)bh * SEQ * D;
  const ushort* kp = kg + (size_t)bh * SEQ * D;
  const ushort* vp = vtg + (size_t)bh * D * SEQ;
  ushort* Ksg = Ks0 + grp * 64 * LDK;
  ushort* Vsg = Vs0 + grp * 64 * LDK;

  const int qrow0 = qt * 128 + wq * 32;
  // Q as B-operand: qf[ds] lane holds Q[qrow0+l31][ds*16 + hi*8 + j]
  bf16x8 qf[4];
#pragma unroll
  for (int ds = 0; ds < 4; ++ds)
    qf[ds] =
        *(const bf16x8*)&qp[(size_t)(qrow0 + l31) * D + ds * 16 + hi * 8];

  f32x16 o[2];
  o[0] = 0.f;
  o[1] = 0.f;
  float l_r = 0.f;  // per-lane partial row-sum for q = qrow0 + l31

  const int r0 = gtid >> 3, c0 = (gtid & 7) * 8;  // group staging slots
  const int r1 = 32 + r0;

  // preload tile it=0 (kt = grp)
  uint4 pk0 = *(const uint4*)&kp[(size_t)grp * 64 * D + r0 * 64 + c0];
  uint4 pk1 = *(const uint4*)&kp[(size_t)grp * 64 * D + r1 * 64 + c0];
  uint4 pv0 = *(const uint4*)&vp[(size_t)r0 * SEQ + grp * 64 + c0];
  uint4 pv1 = *(const uint4*)&vp[(size_t)r1 * SEQ + grp * 64 + c0];

  for (int it = 0; it < SEQ / 128; ++it) {
    __syncthreads();  // prev iter's frag reads done (both groups)
    *(uint4*)&Ksg[r0 * LDK + c0] = pk0;
    *(uint4*)&Ksg[r1 * LDK + c0] = pk1;
    *(uint4*)&Vsg[r0 * LDK + c0] = pv0;
    *(uint4*)&Vsg[r1 * LDK + c0] = pv1;
    __syncthreads();

    // issue NEXT tile's loads; latency hides under this tile's compute
    {
      const int itn = (it + 1 < SEQ / 128) ? it + 1 : it;
      const int ktn = itn * 2 + grp;
      const ushort* ksrc = kp + (size_t)ktn * 64 * D;
      pk0 = *(const uint4*)&ksrc[r0 * 64 + c0];
      pk1 = *(const uint4*)&ksrc[r1 * 64 + c0];
      pv0 = *(const uint4*)&vp[(size_t)r0 * SEQ + ktn * 64 + c0];
      pv1 = *(const uint4*)&vp[(size_t)r1 * SEQ + ktn * 64 + c0];
    }

#pragma unroll
    for (int t = 0; t < 2; ++t) {  // two 32-k tiles per 64-k group tile
      // S^T tile = K·Q^T (32x32), accumulate over d
      f32x16 st = 0.f;
      __builtin_amdgcn_s_setprio(1);
#pragma unroll
      for (int ds = 0; ds < 4; ++ds) {
        bf16x8 kf =
            *(const bf16x8*)&Ksg[(t * 32 + l31) * LDK + ds * 16 + hi * 8];
        st = __builtin_amdgcn_mfma_f32_32x32x16_bf16(kf, qf[ds], st, 0, 0, 0);
      }
      __builtin_amdgcn_s_setprio(0);

      // max-free softmax: p = exp2(score), pairwise row-sum
      float pv[16];
#pragma unroll
      for (int r = 0; r < 16; ++r) pv[r] = fexp2(st[r]);
      {
        float s01 = (pv[0] + pv[1]) + (pv[2] + pv[3]);
        float s23 = (pv[4] + pv[5]) + (pv[6] + pv[7]);
        float s45 = (pv[8] + pv[9]) + (pv[10] + pv[11]);
        float s67 = (pv[12] + pv[13]) + (pv[14] + pv[15]);
        l_r += (s01 + s23) + (s45 + s67);
      }

      // build PV A-frags in-register: per (s,j): pack the tau=0 and tau=1
      // words, swap halves -> word j (src half 0) and word 2+j (src half 1)
      unsigned w0[4], w1[4];
#pragma unroll
      for (int j = 0; j < 2; ++j) {
        {  // s = 0
          unsigned c0w = pk_bf16(pv[2 * j + 0], pv[2 * j + 1]);
          unsigned c1w = pk_bf16(pv[2 * j + 4], pv[2 * j + 5]);
          permswap32(c0w, c1w);
          w0[j] = c0w;
          w0[2 + j] = c1w;
        }
        {  // s = 1
          unsigned c0w = pk_bf16(pv[2 * j + 8], pv[2 * j + 9]);
          unsigned c1w = pk_bf16(pv[2 * j + 12], pv[2 * j + 13]);
          permswap32(c0w, c1w);
          w1[j] = c0w;
          w1[2 + j] = c1w;
        }
      }
      bf16x8 pf0 =
          __builtin_bit_cast(bf16x8, (uint4v){w0[0], w0[1], w0[2], w0[3]});
      bf16x8 pf1 =
          __builtin_bit_cast(bf16x8, (uint4v){w1[0], w1[1], w1[2], w1[3]});

      // O += P·V over this 32-k tile (two 16-k steps), both 32-d halves
      __builtin_amdgcn_s_setprio(1);
#pragma unroll
      for (int nt = 0; nt < 2; ++nt) {
        bf16x8 vf0 =
            *(const bf16x8*)&Vsg[(nt * 32 + l31) * LDK + t * 32 + hi * 8];
        o[nt] = __builtin_amdgcn_mfma_f32_32x32x16_bf16(pf0, vf0, o[nt], 0, 0,
                                                        0);
        bf16x8 vf1 = *(const bf16x8*)&Vsg[(nt * 32 + l31) * LDK + t * 32 + 16 +
                                          hi * 8];
        o[nt] = __builtin_amdgcn_mfma_f32_32x32x16_bf16(pf1, vf1, o[nt], 0, 0,
                                                        0);
      }
      __builtin_amdgcn_s_setprio(0);
    }
  }

  // ---- combine the two K-halves (additive: no max bookkeeping) ----
  __syncthreads();  // all waves done with Ks/Vs before Oex overlay
  float lg = l_r + __shfl_xor(l_r, 32);  // both k-subsets of this group
  float* Oex = (float*)sm;               // [128 q][64 d], stride 68 floats
  if (grp == 1) {
#pragma unroll
    for (int nt = 0; nt < 2; ++nt)
#pragma unroll
      for (int r = 0; r < 16; ++r) {
        int row = (r & 3) + 8 * (r >> 2) + 4 * hi;
        Oex[(wq * 32 + row) * 68 + nt * 32 + l31] = o[nt][r];
      }
    if (lane < 32) lex[wq * 32 + l31] = lg;
  }
  __syncthreads();
  if (grp == 0) {
    float linv = 1.f / (lg + lex[wq * 32 + l31]);
    const int b = bh >> 3, h = bh & 7;
#pragma unroll
    for (int r = 0; r < 16; ++r) {
      int row = (r & 3) + 8 * (r >> 2) + 4 * hi;
      float inv = __shfl(linv, row);  // lane `row` owns q = qrow0 + row
      int srow = qt * 128 + wq * 32 + row;
#pragma unroll
      for (int nt = 0; nt < 2; ++nt) {
        float val = o[nt][r] + Oex[(wq * 32 + row) * 68 + nt * 32 + l31];
        out[((size_t)b * SEQ + srow) * E + h * D + nt * 32 + l31] = val * inv;
      }
    }
  }
}

// ---------------------------------------------------------------------------
extern "C" void kernel_launch(void* const* d_in, const int* in_sizes, int n_in,
                              void* d_out, int out_size, void* d_ws,
                              size_t ws_size, hipStream_t stream) {
  const float* rot = (const float*)d_in[0];
  const float* ent = (const float*)d_in[1];
  const float* x = (const float*)d_in[2];
  const float* wq = (const float*)d_in[3];
  const float* wk = (const float*)d_in[4];
  const float* wv = (const float*)d_in[5];
  float* out = (float*)d_out;

  const size_t NX = (size_t)BATCH * SEQ * E;  // 4M elements
  ushort* weffbT = (ushort*)d_ws;             // 3*E*E bf16 (1.5 MB)
  ushort* xh = weffbT + 3 * E * E;
  ushort* xl = xh + NX;
  ushort* qg = xl + NX;
  ushort* kg = qg + NX;
  ushort* vtg = kg + NX;

  xcast<<<dim3(NX / 1024), 256, 0, stream>>>(x, xh, xl);
  fold_tiled<<<dim3(E / 256, E / 8, 2), 256, 0, stream>>>(wq, wk, rot, ent,
                                                          weffbT);
  wv_cast<<<dim3(E * E / 1024), 256, 0, stream>>>(wv, weffbT + 2 * E * E);
  qkv_fused<<<dim3(H, BATCH * SEQ / 64), 256, 0, stream>>>(xh, xl, weffbT, qg,
                                                           kg, vtg);
  attn_mfma<<<dim3(SEQ / 128, BATCH * H), 512, 0, stream>>>(qg, kg, vtg, out);
}